// Round 3
// baseline (533.352 us; speedup 1.0000x reference)
//
#include <hip/hip_runtime.h>

#define NTHREADS 512
#define TILE 64
#define HALO 12
#define REGN 88      // TILE + 2*HALO
#define STR  92      // padded LDS row stride (floats)
#define NITER 11     // 1 initial + NUM_ITER=10
#define IMG  1024
#define NTILE (IMG / TILE)
#define KROWS 5      // rows per pass-1 job; max jobs = 22*18 = 396 <= 512
#define PR 2         // patch rows per thread (2x4 patch)

// Row 3-min of S[row][x0..x0+3]; left/right neighbors come from the adjacent
// lane's float4 via shfl (conflict-free); edge lanes fall back to a scalar read.
__device__ __forceinline__ void rowmin_s(const float* __restrict__ row,
                                         int x0, int xl, int xr,
                                         bool lv, bool rv, float m[4]) {
    float4 v = *(const float4*)(row + x0);
    float l = __shfl_up(v.w, 1);
    float r = __shfl_down(v.x, 1);
    if (!lv) l = row[xl];
    if (!rv) r = row[xr];
    m[0] = fminf(fminf(l,   v.x), v.y);
    m[1] = fminf(fminf(v.x, v.y), v.z);
    m[2] = fminf(fminf(v.y, v.z), v.w);
    m[3] = fminf(fminf(v.z, v.w), r);
}

__device__ __forceinline__ void rowmax_s(const float* __restrict__ row,
                                         int x0, int xl, int xr,
                                         bool lv, bool rv, float m[4]) {
    float4 v = *(const float4*)(row + x0);
    float l = __shfl_up(v.w, 1);
    float r = __shfl_down(v.x, 1);
    if (!lv) l = row[xl];
    if (!rv) r = row[xr];
    m[0] = fmaxf(fmaxf(l,   v.x), v.y);
    m[1] = fmaxf(fmaxf(v.x, v.y), v.z);
    m[2] = fmaxf(fmaxf(v.y, v.z), v.w);
    m[3] = fmaxf(fmaxf(v.z, v.w), r);
}

// ws[0] = sum(skel_pred * target), ws[1] = sum(skel_pred)
// ws[2] = sum(skel_target * sigmoid(pred)), ws[3] = sum(skel_target)
__global__ __launch_bounds__(NTHREADS, 8)
void cldice_main(const float* __restrict__ pred,
                 const float* __restrict__ target,
                 double* __restrict__ ws)
{
    __shared__ __align__(16) float S[REGN][STR];   // 32384 B -> 5 blocks/CU LDS cap
    __shared__ double red[16];

    const int tid  = threadIdx.x;
    const int lane = tid & 63;
    const int tx = blockIdx.x, ty = blockIdx.y;
    const int b = blockIdx.z >> 1, phase = blockIdx.z & 1;
    const int oy = ty * TILE - HALO;
    const int ox = tx * TILE - HALO;
    const size_t base = (size_t)b * (size_t)(IMG * IMG);
    const float* __restrict__ src = phase ? target : pred;  // img source
    const float* __restrict__ oth = phase ? pred : target;  // multiplied tensor

    const float PINF =  __builtin_huge_valf();
    const float NINF = -__builtin_huge_valf();

    const int ylo = max(0, -oy), yhi = min(REGN, IMG - oy);
    const int xlo = max(0, -ox), xhi = min(REGN, IMG - ox);
    const bool border = (ylo > 0) || (yhi < REGN) || (xlo > 0) || (xhi < REGN);

    // ---- initial load (sigmoid(pred) for phase 0, raw target for 1); OOB = +inf
    for (int i = tid; i < REGN * REGN; i += NTHREADS) {
        int ly = i / REGN, lx = i - ly * REGN;
        int gy = oy + ly, gx = ox + lx;
        float v = PINF;
        if ((unsigned)gy < (unsigned)IMG && (unsigned)gx < (unsigned)IMG) {
            float rr = src[base + (size_t)gy * IMG + gx];
            v = phase ? rr : 1.0f / (1.0f + __expf(-rr));
        }
        S[ly][lx] = v;
    }
    __syncthreads();

    float skel[PR][4];
#pragma unroll
    for (int r = 0; r < PR; ++r)
#pragma unroll
        for (int j = 0; j < 4; ++j) skel[r][j] = 0.0f;

    const int rg = (tid >> 4) << 1;   // output row base in tile (0..62 step 2)
    const int cc = (tid & 15) << 2;   // output col base in tile
    const int ly0 = HALO + rg;
    const int lx0 = HALO + cc;
    const bool lv2 = (tid & 15) != 0;
    const bool rv2 = (tid & 15) != 15;

#pragma unroll 1
    for (int it = 0; it < NITER; ++it) {
        const int row0   = it + 1;        // first erode output row
        const int rowEnd = 87 - it;       // exclusive
        const int c0 = row0 >> 2;
        const int c1 = (rowEnd - 1) >> 2;
        const int nch = c1 - c0 + 1;
        const int nrb = (rowEnd - row0 + KROWS - 1) / KROWS;
        const int njobs = nch * nrb;

        const int rb = tid / nch;
        const int ci = tid - rb * nch;
        const int x0 = (c0 + ci) << 2;
        const int r0 = row0 + rb * KROWS;
        const bool act = tid < njobs;
        const bool lv = (ci != 0) && (lane != 0);
        const bool rv = (ci != nch - 1) && (lane != 63);
        const int xl = max(x0 - 1, 0);
        const int xr = min(x0 + 4, REGN - 1);

        // ---- pass 1: erode(S) into registers (uniform trip so shfl is legal)
        float er_[KROWS][4];
        {
            float A[4], B[4];
            rowmin_s(&S[min(r0 - 1, REGN - 1)][0], x0, xl, xr, lv, rv, A);
            rowmin_s(&S[min(r0,     REGN - 1)][0], x0, xl, xr, lv, rv, B);
#pragma unroll
            for (int jj = 0; jj < KROWS; ++jj) {
                float C[4];
                rowmin_s(&S[min(r0 + jj + 1, REGN - 1)][0], x0, xl, xr, lv, rv, C);
#pragma unroll
                for (int j = 0; j < 4; ++j) {
                    er_[jj][j] = fminf(fminf(A[j], B[j]), C[j]);
                    A[j] = B[j]; B[j] = C[j];
                }
            }
        }

        // save e at own patch (needed for delta after S is overwritten)
        float4 ep[PR];
#pragma unroll
        for (int r = 0; r < PR; ++r)
            ep[r] = *(const float4*)&S[ly0 + r][lx0];

        __syncthreads();   // all reads of e done

        // ---- write back er (border blocks substitute NINF at image-OOB cells)
        if (act) {
            const bool cv0 = (x0     >= xlo) && (x0     < xhi);
            const bool cv1 = (x0 + 1 >= xlo) && (x0 + 1 < xhi);
            const bool cv2 = (x0 + 2 >= xlo) && (x0 + 2 < xhi);
            const bool cv3 = (x0 + 3 >= xlo) && (x0 + 3 < xhi);
#pragma unroll
            for (int jj = 0; jj < KROWS; ++jj) {
                int r = r0 + jj;
                if (r < rowEnd) {
                    float4 w;
                    w.x = er_[jj][0]; w.y = er_[jj][1];
                    w.z = er_[jj][2]; w.w = er_[jj][3];
                    if (border) {
                        bool rOOB = (r < ylo) || (r >= yhi);
                        w.x = (rOOB || !cv0) ? NINF : w.x;
                        w.y = (rOOB || !cv1) ? NINF : w.y;
                        w.z = (rOOB || !cv2) ? NINF : w.z;
                        w.w = (rOOB || !cv3) ? NINF : w.w;
                    }
                    *(float4*)&S[r][x0] = w;
                }
            }
        }
        __syncthreads();   // er visible

        // ---- pass 2: open = maxpool(er); delta; skel update (all in registers)
        {
            float A[4], B[4];
            rowmax_s(&S[ly0 - 1][0], lx0, lx0 - 1, lx0 + 4, lv2, rv2, A);
            rowmax_s(&S[ly0][0],     lx0, lx0 - 1, lx0 + 4, lv2, rv2, B);
#pragma unroll
            for (int r = 0; r < PR; ++r) {
                float C[4];
                rowmax_s(&S[ly0 + r + 1][0], lx0, lx0 - 1, lx0 + 4, lv2, rv2, C);
                float e4[4] = {ep[r].x, ep[r].y, ep[r].z, ep[r].w};
#pragma unroll
                for (int j = 0; j < 4; ++j) {
                    float op = fmaxf(fmaxf(A[j], B[j]), C[j]);
                    float d  = fmaxf(e4[j] - op, 0.0f);
                    skel[r][j] += fmaxf(d - skel[r][j] * d, 0.0f);
                    A[j] = B[j]; B[j] = C[j];
                }
            }
        }

        // ---- border: restore +inf on OOB cells within next iteration's read range
        if (border && it != NITER - 1) {
            __syncthreads();   // pass-2 reads done
            const int lo = it + 1, hi = 86 - it;   // next pass-1 read range (incl)
            const int NR = hi - lo + 1;
            const int W  = 12 - lo;                // strip width = 11 - it
            if (tx == 0) {
                for (int i = tid; i < W * NR; i += NTHREADS) {
                    int rr = i / W, c2 = i - rr * W;
                    S[lo + rr][lo + c2] = PINF;    // cols [lo, 11]
                }
            }
            if (tx == NTILE - 1) {
                for (int i = tid; i < W * NR; i += NTHREADS) {
                    int rr = i / W, c2 = i - rr * W;
                    S[lo + rr][76 + c2] = PINF;    // cols [76, hi]
                }
            }
            if (ty == 0) {
                for (int i = tid; i < W * NR; i += NTHREADS) {
                    int rr = i / NR, c2 = i - rr * NR;
                    S[lo + rr][lo + c2] = PINF;    // rows [lo, 11]
                }
            }
            if (ty == NTILE - 1) {
                for (int i = tid; i < W * NR; i += NTHREADS) {
                    int rr = i / NR, c2 = i - rr * NR;
                    S[76 + rr][lo + c2] = PINF;    // rows [76, hi]
                }
            }
            __syncthreads();   // PINF visible before next pass-1 reads
        }
    }

    // ---- sums: sp = sum(skel * other), ss = sum(skel)
    float spf = 0.0f, ssf = 0.0f;
    const int gy0 = ty * TILE + rg;
    const int gx0 = tx * TILE + cc;
#pragma unroll
    for (int r = 0; r < PR; ++r) {
        float4 o = *(const float4*)&oth[base + (size_t)(gy0 + r) * IMG + gx0];
        float ov[4] = {o.x, o.y, o.z, o.w};
#pragma unroll
        for (int j = 0; j < 4; ++j) {
            float x = ov[j];
            if (phase) x = 1.0f / (1.0f + __expf(-x));  // pred_prob
            spf += skel[r][j] * x;
            ssf += skel[r][j];
        }
    }
    double sp = (double)spf, ss = (double)ssf;
#pragma unroll
    for (int off = 32; off > 0; off >>= 1) {
        sp += __shfl_down(sp, off);
        ss += __shfl_down(ss, off);
    }
    const int wave = tid >> 6;
    if (lane == 0) { red[wave * 2] = sp; red[wave * 2 + 1] = ss; }
    __syncthreads();
    if (tid == 0) {
        double tsp = 0.0, tss = 0.0;
#pragma unroll
        for (int w = 0; w < NTHREADS / 64; ++w) { tsp += red[w * 2]; tss += red[w * 2 + 1]; }
        atomicAdd(&ws[phase * 2],     tsp);
        atomicAdd(&ws[phase * 2 + 1], tss);
    }
}

__global__ void cldice_zero(double* __restrict__ ws) {
    if (threadIdx.x < 4) ws[threadIdx.x] = 0.0;
}

__global__ void cldice_final(const double* __restrict__ ws,
                             float* __restrict__ out) {
    if (threadIdx.x == 0 && blockIdx.x == 0) {
        double tprec = (ws[0] + 1.0) / (ws[1] + 1.0);
        double tsens = (ws[2] + 1.0) / (ws[3] + 1.0);
        double cl = 2.0 * tprec * tsens / (tprec + tsens + 1e-7);
        out[0] = (float)(1.0 - cl);
    }
}

extern "C" void kernel_launch(void* const* d_in, const int* in_sizes, int n_in,
                              void* d_out, int out_size, void* d_ws, size_t ws_size,
                              hipStream_t stream) {
    const float* pred   = (const float*)d_in[0];
    const float* target = (const float*)d_in[1];
    double* ws = (double*)d_ws;
    float* out = (float*)d_out;

    cldice_zero<<<dim3(1), dim3(64), 0, stream>>>(ws);
    cldice_main<<<dim3(NTILE, NTILE, 8 * 2), dim3(NTHREADS), 0, stream>>>(
        pred, target, ws);
    cldice_final<<<dim3(1), dim3(64), 0, stream>>>(ws, out);
}

// Round 4
// 421.053 us; speedup vs baseline: 1.2667x; 1.2667x over previous
//
#include <hip/hip_runtime.h>

#define NTHREADS 512
#define TILE 64
#define HALO 12
#define REGN 88      // TILE + 2*HALO
#define STR  92      // padded LDS row stride (floats)
#define NITER 11     // 1 initial + NUM_ITER=10
#define IMG  1024
#define NTILE (IMG / TILE)
#define KROWS 5      // rows per pass-1 job; max jobs = 22*18 = 396 <= 512
#define PR 2         // patch rows per thread (2x4 patch)

// Row 3-min of S[row][x0..x0+3]; left/right neighbors come from the adjacent
// lane's float4 via shfl (conflict-free); edge lanes fall back to a scalar read.
__device__ __forceinline__ void rowmin_s(const float* __restrict__ row,
                                         int x0, int xl, int xr,
                                         bool lv, bool rv, float m[4]) {
    float4 v = *(const float4*)(row + x0);
    float l = __shfl_up(v.w, 1);
    float r = __shfl_down(v.x, 1);
    if (!lv) l = row[xl];
    if (!rv) r = row[xr];
    m[0] = fminf(fminf(l,   v.x), v.y);
    m[1] = fminf(fminf(v.x, v.y), v.z);
    m[2] = fminf(fminf(v.y, v.z), v.w);
    m[3] = fminf(fminf(v.z, v.w), r);
}

__device__ __forceinline__ void rowmax_s(const float* __restrict__ row,
                                         int x0, int xl, int xr,
                                         bool lv, bool rv, float m[4]) {
    float4 v = *(const float4*)(row + x0);
    float l = __shfl_up(v.w, 1);
    float r = __shfl_down(v.x, 1);
    if (!lv) l = row[xl];
    if (!rv) r = row[xr];
    m[0] = fmaxf(fmaxf(l,   v.x), v.y);
    m[1] = fmaxf(fmaxf(v.x, v.y), v.z);
    m[2] = fmaxf(fmaxf(v.y, v.z), v.w);
    m[3] = fmaxf(fmaxf(v.z, v.w), r);
}

// ws[0] = sum(skel_pred * target), ws[1] = sum(skel_pred)
// ws[2] = sum(skel_target * sigmoid(pred)), ws[3] = sum(skel_target)
// launch_bounds(512,4): VGPR cap ~128 -> no spill (kernel needs ~65);
// at the actual ~64-reg allocation HW still allows 8 waves/SIMD.
__global__ __launch_bounds__(NTHREADS, 4)
void cldice_main(const float* __restrict__ pred,
                 const float* __restrict__ target,
                 double* __restrict__ ws)
{
    __shared__ __align__(16) float S[REGN][STR];   // 32384 B
    __shared__ double red[16];

    const int tid  = threadIdx.x;
    const int lane = tid & 63;
    const int tx = blockIdx.x, ty = blockIdx.y;
    const int b = blockIdx.z >> 1, phase = blockIdx.z & 1;
    const int oy = ty * TILE - HALO;
    const int ox = tx * TILE - HALO;
    const size_t base = (size_t)b * (size_t)(IMG * IMG);
    const float* __restrict__ src = phase ? target : pred;  // img source
    const float* __restrict__ oth = phase ? pred : target;  // multiplied tensor

    const float PINF =  __builtin_huge_valf();
    const float NINF = -__builtin_huge_valf();

    const int ylo = max(0, -oy), yhi = min(REGN, IMG - oy);
    const int xlo = max(0, -ox), xhi = min(REGN, IMG - ox);
    const bool border = (ylo > 0) || (yhi < REGN) || (xlo > 0) || (xhi < REGN);

    // ---- initial load (sigmoid(pred) for phase 0, raw target for 1); OOB = +inf
    for (int i = tid; i < REGN * REGN; i += NTHREADS) {
        int ly = i / REGN, lx = i - ly * REGN;
        int gy = oy + ly, gx = ox + lx;
        float v = PINF;
        if ((unsigned)gy < (unsigned)IMG && (unsigned)gx < (unsigned)IMG) {
            float rr = src[base + (size_t)gy * IMG + gx];
            v = phase ? rr : 1.0f / (1.0f + __expf(-rr));
        }
        S[ly][lx] = v;
    }
    __syncthreads();

    float skel[PR][4];
#pragma unroll
    for (int r = 0; r < PR; ++r)
#pragma unroll
        for (int j = 0; j < 4; ++j) skel[r][j] = 0.0f;

    const int rg = (tid >> 4) << 1;   // output row base in tile (0..62 step 2)
    const int cc = (tid & 15) << 2;   // output col base in tile
    const int ly0 = HALO + rg;
    const int lx0 = HALO + cc;
    const bool lv2 = (tid & 15) != 0;
    const bool rv2 = (tid & 15) != 15;

#pragma unroll 1
    for (int it = 0; it < NITER; ++it) {
        const int row0   = it + 1;        // first erode output row
        const int rowEnd = 87 - it;       // exclusive
        const int c0 = row0 >> 2;
        const int c1 = (rowEnd - 1) >> 2;
        const int nch = c1 - c0 + 1;
        const int nrb = (rowEnd - row0 + KROWS - 1) / KROWS;
        const int njobs = nch * nrb;

        const int rb = tid / nch;
        const int ci = tid - rb * nch;
        const int x0 = (c0 + ci) << 2;
        const int r0 = row0 + rb * KROWS;
        const bool act = tid < njobs;
        const bool lv = (ci != 0) && (lane != 0);
        const bool rv = (ci != nch - 1) && (lane != 63);
        const int xl = max(x0 - 1, 0);
        const int xr = min(x0 + 4, REGN - 1);

        // ---- pass 1: erode(S) into registers (uniform trip so shfl is legal)
        float er_[KROWS][4];
        {
            float A[4], B[4];
            rowmin_s(&S[min(r0 - 1, REGN - 1)][0], x0, xl, xr, lv, rv, A);
            rowmin_s(&S[min(r0,     REGN - 1)][0], x0, xl, xr, lv, rv, B);
#pragma unroll
            for (int jj = 0; jj < KROWS; ++jj) {
                float C[4];
                rowmin_s(&S[min(r0 + jj + 1, REGN - 1)][0], x0, xl, xr, lv, rv, C);
#pragma unroll
                for (int j = 0; j < 4; ++j) {
                    er_[jj][j] = fminf(fminf(A[j], B[j]), C[j]);
                    A[j] = B[j]; B[j] = C[j];
                }
            }
        }

        // save e at own patch (needed for delta after S is overwritten)
        float4 ep[PR];
#pragma unroll
        for (int r = 0; r < PR; ++r)
            ep[r] = *(const float4*)&S[ly0 + r][lx0];

        __syncthreads();   // all reads of e done

        // ---- write back er (border blocks substitute NINF at image-OOB cells)
        if (act) {
            const bool cv0 = (x0     >= xlo) && (x0     < xhi);
            const bool cv1 = (x0 + 1 >= xlo) && (x0 + 1 < xhi);
            const bool cv2 = (x0 + 2 >= xlo) && (x0 + 2 < xhi);
            const bool cv3 = (x0 + 3 >= xlo) && (x0 + 3 < xhi);
#pragma unroll
            for (int jj = 0; jj < KROWS; ++jj) {
                int r = r0 + jj;
                if (r < rowEnd) {
                    float4 w;
                    w.x = er_[jj][0]; w.y = er_[jj][1];
                    w.z = er_[jj][2]; w.w = er_[jj][3];
                    if (border) {
                        bool rOOB = (r < ylo) || (r >= yhi);
                        w.x = (rOOB || !cv0) ? NINF : w.x;
                        w.y = (rOOB || !cv1) ? NINF : w.y;
                        w.z = (rOOB || !cv2) ? NINF : w.z;
                        w.w = (rOOB || !cv3) ? NINF : w.w;
                    }
                    *(float4*)&S[r][x0] = w;
                }
            }
        }
        __syncthreads();   // er visible

        // ---- pass 2: open = maxpool(er); delta; skel update (all in registers)
        {
            float A[4], B[4];
            rowmax_s(&S[ly0 - 1][0], lx0, lx0 - 1, lx0 + 4, lv2, rv2, A);
            rowmax_s(&S[ly0][0],     lx0, lx0 - 1, lx0 + 4, lv2, rv2, B);
#pragma unroll
            for (int r = 0; r < PR; ++r) {
                float C[4];
                rowmax_s(&S[ly0 + r + 1][0], lx0, lx0 - 1, lx0 + 4, lv2, rv2, C);
                float e4[4] = {ep[r].x, ep[r].y, ep[r].z, ep[r].w};
#pragma unroll
                for (int j = 0; j < 4; ++j) {
                    float op = fmaxf(fmaxf(A[j], B[j]), C[j]);
                    float d  = fmaxf(e4[j] - op, 0.0f);
                    skel[r][j] += fmaxf(d - skel[r][j] * d, 0.0f);
                    A[j] = B[j]; B[j] = C[j];
                }
            }
        }

        // ---- border: restore +inf on OOB cells within next iteration's read range
        if (border && it != NITER - 1) {
            __syncthreads();   // pass-2 reads done
            const int lo = it + 1, hi = 86 - it;   // next pass-1 read range (incl)
            const int NR = hi - lo + 1;
            const int W  = 12 - lo;                // strip width = 11 - it
            if (tx == 0) {
                for (int i = tid; i < W * NR; i += NTHREADS) {
                    int rr = i / W, c2 = i - rr * W;
                    S[lo + rr][lo + c2] = PINF;    // cols [lo, 11]
                }
            }
            if (tx == NTILE - 1) {
                for (int i = tid; i < W * NR; i += NTHREADS) {
                    int rr = i / W, c2 = i - rr * W;
                    S[lo + rr][76 + c2] = PINF;    // cols [76, hi]
                }
            }
            if (ty == 0) {
                for (int i = tid; i < W * NR; i += NTHREADS) {
                    int rr = i / NR, c2 = i - rr * NR;
                    S[lo + rr][lo + c2] = PINF;    // rows [lo, 11]
                }
            }
            if (ty == NTILE - 1) {
                for (int i = tid; i < W * NR; i += NTHREADS) {
                    int rr = i / NR, c2 = i - rr * NR;
                    S[76 + rr][lo + c2] = PINF;    // rows [76, hi]
                }
            }
            __syncthreads();   // PINF visible before next pass-1 reads
        }
    }

    // ---- sums: sp = sum(skel * other), ss = sum(skel)
    float spf = 0.0f, ssf = 0.0f;
    const int gy0 = ty * TILE + rg;
    const int gx0 = tx * TILE + cc;
#pragma unroll
    for (int r = 0; r < PR; ++r) {
        float4 o = *(const float4*)&oth[base + (size_t)(gy0 + r) * IMG + gx0];
        float ov[4] = {o.x, o.y, o.z, o.w};
#pragma unroll
        for (int j = 0; j < 4; ++j) {
            float x = ov[j];
            if (phase) x = 1.0f / (1.0f + __expf(-x));  // pred_prob
            spf += skel[r][j] * x;
            ssf += skel[r][j];
        }
    }
    double sp = (double)spf, ss = (double)ssf;
#pragma unroll
    for (int off = 32; off > 0; off >>= 1) {
        sp += __shfl_down(sp, off);
        ss += __shfl_down(ss, off);
    }
    const int wave = tid >> 6;
    if (lane == 0) { red[wave * 2] = sp; red[wave * 2 + 1] = ss; }
    __syncthreads();
    if (tid == 0) {
        double tsp = 0.0, tss = 0.0;
#pragma unroll
        for (int w = 0; w < NTHREADS / 64; ++w) { tsp += red[w * 2]; tss += red[w * 2 + 1]; }
        atomicAdd(&ws[phase * 2],     tsp);
        atomicAdd(&ws[phase * 2 + 1], tss);
    }
}

__global__ void cldice_zero(double* __restrict__ ws) {
    if (threadIdx.x < 4) ws[threadIdx.x] = 0.0;
}

__global__ void cldice_final(const double* __restrict__ ws,
                             float* __restrict__ out) {
    if (threadIdx.x == 0 && blockIdx.x == 0) {
        double tprec = (ws[0] + 1.0) / (ws[1] + 1.0);
        double tsens = (ws[2] + 1.0) / (ws[3] + 1.0);
        double cl = 2.0 * tprec * tsens / (tprec + tsens + 1e-7);
        out[0] = (float)(1.0 - cl);
    }
}

extern "C" void kernel_launch(void* const* d_in, const int* in_sizes, int n_in,
                              void* d_out, int out_size, void* d_ws, size_t ws_size,
                              hipStream_t stream) {
    const float* pred   = (const float*)d_in[0];
    const float* target = (const float*)d_in[1];
    double* ws = (double*)d_ws;
    float* out = (float*)d_out;

    cldice_zero<<<dim3(1), dim3(64), 0, stream>>>(ws);
    cldice_main<<<dim3(NTILE, NTILE, 8 * 2), dim3(NTHREADS), 0, stream>>>(
        pred, target, ws);
    cldice_final<<<dim3(1), dim3(64), 0, stream>>>(ws, out);
}